// Round 7
// baseline (1058.176 us; speedup 1.0000x reference)
//
#include <hip/hip_runtime.h>
#include <stdint.h>

#define N 8192
#define D 512
#define NEG -1e30f

typedef _Float16 f16;
typedef f16 f16x4 __attribute__((ext_vector_type(4)));
typedef f16 f16x8 __attribute__((ext_vector_type(8)));
typedef float f32x4v __attribute__((ext_vector_type(4)));
typedef float f32x16 __attribute__((ext_vector_type(16)));

// ---- workspace layout (bytes) ----
#define XH_OFF  0ull
#define WQH_OFF (XH_OFF + 8192ull * 512 * 2)
#define WKH_OFF (WQH_OFF + 512ull * 512 * 2)
#define WVH_OFF (WKH_OFF + 512ull * 512 * 2)
#define QH_OFF  (WVH_OFF + 512ull * 512 * 2)
#define KH_OFF  (QH_OFF + 8192ull * 512 * 2)
#define VT_OFF  (KH_OFF + 8192ull * 512 * 2)
#define P1_OFF  (VT_OFF + 8192ull * 512 * 2)        // half-1 partial, fp32, 16 MB
#define ML_OFF  (P1_OFF + 8192ull * 512 * 4)        // float2 ml[2][8192]

// attn LDS: Qs 64 rows x 1040 B (stride 65*16B -> conflict-free) + 4 wave P slabs
#define QROW   1040
#define QS_SZ  (64 * QROW)          // 66560
#define PSLAB  1280                 // 16 rows x 80 B
#define LDSB   (QS_SZ + 4 * PSLAB)  // 71680 -> 2 blocks/CU

// ---------------- fp32 -> fp16 conversion (X and the three W's) ----------------
__global__ __launch_bounds__(256) void cvt_fp16(
    const float* __restrict__ X,
    const float* __restrict__ Wq, const float* __restrict__ Wk, const float* __restrict__ Wv,
    f16* __restrict__ Xh,
    f16* __restrict__ Wqh, f16* __restrict__ Wkh, f16* __restrict__ Wvh)
{
    const int idx = blockIdx.x * 256 + threadIdx.x;
    const float* src; f16* dst; int off;
    if (idx < 1048576)      { src = X;  dst = Xh;  off = idx; }
    else if (idx < 1114112) { src = Wq; dst = Wqh; off = idx - 1048576; }
    else if (idx < 1179648) { src = Wk; dst = Wkh; off = idx - 1114112; }
    else                    { src = Wv; dst = Wvh; off = idx - 1179648; }
    const float4 v = ((const float4*)src)[off];
    f16x4 h; h.x = (f16)v.x; h.y = (f16)v.y; h.z = (f16)v.z; h.w = (f16)v.w;
    *(f16x4*)(dst + (size_t)off * 4) = h;
}

// ---------------- QKV via MFMA (unchanged from round 4) ----------------
__global__ __launch_bounds__(256) void qkv_mfma(
    const f16* __restrict__ Xh,
    const f16* __restrict__ Wqh, const f16* __restrict__ Wkh, const f16* __restrict__ Wvh,
    f16* __restrict__ qh, f16* __restrict__ kh, f16* __restrict__ vt)
{
    const int t    = threadIdx.x;
    const int w    = t >> 6;
    const int lane = t & 63;
    const int lo   = lane & 31;
    const int hi   = lane >> 5;
    const int z    = blockIdx.z;

    int m0, c0; const f16 *Ap, *Bp; f16* Yp; size_t ldy;
    if (z == 2) {
        m0 = blockIdx.x * 128 + w * 32; c0 = blockIdx.y * 128;
        Ap = Wvh; Bp = Xh; Yp = vt; ldy = N;
    } else {
        m0 = blockIdx.y * 128 + w * 32; c0 = blockIdx.x * 128;
        Ap = Xh; Bp = z ? Wkh : Wqh; Yp = z ? kh : qh; ldy = D;
    }

    const f16* arow = Ap + (size_t)(m0 + lo) * D + hi * 8;
    const f16* brow[4];
#pragma unroll
    for (int nn = 0; nn < 4; ++nn)
        brow[nn] = Bp + (size_t)(c0 + nn * 32 + lo) * D + hi * 8;

    f32x16 acc[4];
#pragma unroll
    for (int nn = 0; nn < 4; ++nn)
#pragma unroll
        for (int e = 0; e < 16; ++e) acc[nn][e] = 0.f;

#pragma unroll 4
    for (int ks = 0; ks < 32; ++ks) {
        const f16x8 a = *(const f16x8*)(arow + ks * 16);
#pragma unroll
        for (int nn = 0; nn < 4; ++nn) {
            const f16x8 b = *(const f16x8*)(brow[nn] + ks * 16);
            acc[nn] = __builtin_amdgcn_mfma_f32_32x32x16_f16(a, b, acc[nn], 0, 0, 0);
        }
    }

#pragma unroll
    for (int nn = 0; nn < 4; ++nn)
#pragma unroll
        for (int r = 0; r < 16; ++r) {
            const int row = m0 + (r & 3) + 8 * (r >> 2) + 4 * hi;
            Yp[(size_t)row * ldy + c0 + nn * 32 + lo] = (f16)acc[nn][r];
        }
}

// ---------------- attention v2: swapped-QK^T, in-register softmax ----------------
// grid 256. Block: 64 j-rows (4 waves x 16) x one source half (4096 i).
// Wave-private: softmax stats in registers; P slab in wave-private LDS (no barriers
// in the main loop). 16x16x32 MFMA:
//   A[row=l&15][k=(l>>4)*8+e], B[k=(l>>4)*8+e][col=l&15], C col=l&15,row=(l>>4)*4+r.
// QK^T swapped (A=K, B=Q): lane holds S[i=(g*4+r)+16a][j=jl]; row-softmax over i is
// in-lane + shfl_xor(16,32). K/V global fragment loads: 16 rows x 64B contiguous
// per instr (full sector utilization).
__global__ __launch_bounds__(256, 2) void attn_v2(
    const f16* __restrict__ qh, const f16* __restrict__ kh,
    const f16* __restrict__ vt, const int* __restrict__ adj,
    float* __restrict__ p0, float* __restrict__ p1, float2* __restrict__ ml)
{
    extern __shared__ char smem[];
    char* Qs = smem;
    char* Pw = smem + QS_SZ + (threadIdx.x >> 6) * PSLAB;

    const int t    = threadIdx.x;
    const int lane = t & 63;
    const int jl   = lane & 15;   // j_local within wave / d_local / i_local
    const int g    = lane >> 4;   // k-chunk group
    const int w    = t >> 6;

    // XCD-grouped swizzle: XCDs 0-3 -> half 0, XCDs 4-7 -> half 1 (bijective)
    const int b    = blockIdx.x;
    const int rr   = b & 7;
    const int half = rr >> 2;
    const int jb   = (rr & 3) * 32 + (b >> 3);
    const int j0   = jb * 64;
    const int j0w  = j0 + w * 16;
    const int ih0  = half * 4096;
    float* pbuf = half ? p1 : p0;

    // ---- stage Q[j0..j0+63][*] into Qs (row stride 1040 B) ----
    for (int c = t; c < 64 * 64; c += 256) {
        const int row = c >> 6, off = c & 63;
        f16x8 v = *(const f16x8*)(qh + (size_t)(j0 + row) * D + off * 8);
        *(f16x8*)(Qs + row * QROW + off * 16) = v;
    }
    __syncthreads();

    f32x4v oacc[32];
#pragma unroll
    for (int c = 0; c < 32; ++c) { oacc[c][0]=0.f; oacc[c][1]=0.f; oacc[c][2]=0.f; oacc[c][3]=0.f; }
    float m_run = NEG, l_run = 0.f;

    const char* qrd   = Qs + (w * 16 + jl) * QROW + g * 16;
    const f16*  kbase = kh + (size_t)(ih0 + jl) * D + g * 8;
    const f16*  vbase = vt + (size_t)jl * N + ih0 + g * 8;
    const int*  abase = adj + (size_t)(ih0 + g * 4) * N + j0w + jl;
    char* pwr0 = Pw + jl * 80 + g * 8;       // P write, a=0 (a=1 at +32)
    const char* prd = Pw + jl * 80 + g * 16; // P read (A-frag)

    for (int it = 0; it < 128; ++it) {
        const f16* kt = kbase + (size_t)it * 32 * D;
        const int* at = abase + (size_t)it * 32 * N;

        // ---- adjacency masks: valid iff adj[i][j] != 0 ----
        int msk[2][4];
#pragma unroll
        for (int a = 0; a < 2; ++a)
#pragma unroll
            for (int rg = 0; rg < 4; ++rg)
                msk[a][rg] = at[(size_t)(a * 16 + rg) * N];

        // ---- QK^T: S^T accumulators (i rows, j cols) ----
        f32x4v sa0, sa1;
        sa0[0]=0.f;sa0[1]=0.f;sa0[2]=0.f;sa0[3]=0.f;
        sa1[0]=0.f;sa1[1]=0.f;sa1[2]=0.f;sa1[3]=0.f;
#pragma unroll 4
        for (int ks = 0; ks < 16; ++ks) {
            f16x8 qf = *(const f16x8*)(qrd + ks * 64);
            f16x8 k0 = *(const f16x8*)(kt + ks * 32);
            f16x8 k1 = *(const f16x8*)(kt + (size_t)16 * D + ks * 32);
            sa0 = __builtin_amdgcn_mfma_f32_16x16x32_f16(k0, qf, sa0, 0, 0, 0);
            sa1 = __builtin_amdgcn_mfma_f32_16x16x32_f16(k1, qf, sa1, 0, 0, 0);
        }

        // ---- masked in-register online softmax (row j = jl) ----
        float s[2][4];
        float mt = NEG;
#pragma unroll
        for (int rg = 0; rg < 4; ++rg) {
            s[0][rg] = msk[0][rg] ? sa0[rg] : NEG;
            s[1][rg] = msk[1][rg] ? sa1[rg] : NEG;
            mt = fmaxf(mt, fmaxf(s[0][rg], s[1][rg]));
        }
        mt = fmaxf(mt, __shfl_xor(mt, 16, 64));
        mt = fmaxf(mt, __shfl_xor(mt, 32, 64));

        if (__any(mt > m_run)) {           // defer-rescale: skip when max unchanged
            const float m_new = fmaxf(m_run, mt);
            const float sc = __expf(m_run - m_new);
            m_run = m_new;
            l_run *= sc;
            float scr[4];
#pragma unroll
            for (int rg = 0; rg < 4; ++rg) scr[rg] = __shfl(sc, g * 4 + rg, 64);
#pragma unroll
            for (int c = 0; c < 32; ++c) {
                oacc[c][0] *= scr[0]; oacc[c][1] *= scr[1];
                oacc[c][2] *= scr[2]; oacc[c][3] *= scr[3];
            }
        }

        float p[2][4];
        float ps = 0.f;
#pragma unroll
        for (int a = 0; a < 2; ++a)
#pragma unroll
            for (int rg = 0; rg < 4; ++rg) {
                const float pe = msk[a][rg] ? __expf(s[a][rg] - m_run) : 0.f;
                p[a][rg] = pe;
                ps += pe;
            }
        ps += __shfl_xor(ps, 16, 64);
        ps += __shfl_xor(ps, 32, 64);
        l_run += ps;

        // ---- pack P (f16) -> wave-private LDS slab [j=jl][i], stride 80 B ----
        {
            union { f16 h[8]; uint2 u2[2]; } pc;
#pragma unroll
            for (int a = 0; a < 2; ++a)
#pragma unroll
                for (int rg = 0; rg < 4; ++rg)
                    pc.h[a * 4 + rg] = (f16)p[a][rg];
            *(uint2*)(pwr0)      = pc.u2[0];
            *(uint2*)(pwr0 + 32) = pc.u2[1];
        }

        // ---- PV: one A-frag read, 32 d-chunks ----
        const f16x8 pa = *(const f16x8*)(prd);
        const f16* vtile = vbase + it * 32;
#pragma unroll
        for (int c = 0; c < 32; ++c) {
            f16x8 vf = *(const f16x8*)(vtile + (size_t)c * 16 * N);
            oacc[c] = __builtin_amdgcn_mfma_f32_16x16x32_f16(pa, vf, oacc[c], 0, 0, 0);
        }
    }

    // ---- store unnormalized partial (C layout: row=(g*4+rg), col=jl) + ml ----
#pragma unroll
    for (int c = 0; c < 32; ++c)
#pragma unroll
        for (int rg = 0; rg < 4; ++rg)
            pbuf[(size_t)(j0w + g * 4 + rg) * D + c * 16 + jl] = oacc[c][rg];
    if (lane < 16) {
        float2 v; v.x = m_run; v.y = l_run;
        ml[half * N + j0w + lane] = v;
    }
}

// ---------------- merge the two source halves ----------------
__global__ __launch_bounds__(256) void merge_halves(
    float* __restrict__ o0, const float* __restrict__ o1,
    const float2* __restrict__ ml)
{
    const int idx = blockIdx.x * 256 + threadIdx.x;   // one float4 each
    const int j = idx >> 7;
    const float2 a = ml[j];
    const float2 b = ml[N + j];
    const float m  = fmaxf(a.x, b.x);
    const float e0 = __expf(a.x - m);
    const float e1 = __expf(b.x - m);
    const float L  = a.y * e0 + b.y * e1;
    const float inv = (L > 0.f) ? 1.f / L : 0.f;
    const float4 x0 = ((const float4*)o0)[idx];
    const float4 x1 = ((const float4*)o1)[idx];
    float4 r;
    r.x = (x0.x * e0 + x1.x * e1) * inv;
    r.y = (x0.y * e0 + x1.y * e1) * inv;
    r.z = (x0.z * e0 + x1.z * e1) * inv;
    r.w = (x0.w * e0 + x1.w * e1) * inv;
    ((float4*)o0)[idx] = r;
}

extern "C" void kernel_launch(void* const* d_in, const int* in_sizes, int n_in,
                              void* d_out, int out_size, void* d_ws, size_t ws_size,
                              hipStream_t stream) {
    const float* ns  = (const float*)d_in[0];
    const int*   adj = (const int*)d_in[1];
    const float* Wq  = (const float*)d_in[2];
    const float* Wk  = (const float*)d_in[3];
    const float* Wv  = (const float*)d_in[4];

    char* ws = (char*)d_ws;
    f16*    Xh  = (f16*)(ws + XH_OFF);
    f16*    Wqh = (f16*)(ws + WQH_OFF);
    f16*    Wkh = (f16*)(ws + WKH_OFF);
    f16*    Wvh = (f16*)(ws + WVH_OFF);
    f16*    qh  = (f16*)(ws + QH_OFF);
    f16*    kh  = (f16*)(ws + KH_OFF);
    f16*    vt  = (f16*)(ws + VT_OFF);
    float*  p1  = (float*)(ws + P1_OFF);
    float2* mlb = (float2*)(ws + ML_OFF);
    float*  out = (float*)d_out;

    (void)hipFuncSetAttribute((const void*)attn_v2,
                              hipFuncAttributeMaxDynamicSharedMemorySize, LDSB);

    cvt_fp16<<<4864, 256, 0, stream>>>(ns, Wq, Wk, Wv, Xh, Wqh, Wkh, Wvh);
    qkv_mfma<<<dim3(4, 64, 3), 256, 0, stream>>>(Xh, Wqh, Wkh, Wvh, qh, kh, vt);
    attn_v2<<<256, 256, LDSB, stream>>>(qh, kh, vt, adj, out, p1, mlb);
    merge_halves<<<4096, 256, 0, stream>>>(out, p1, mlb);
}